// Round 1
// baseline (391.640 us; speedup 1.0000x reference)
//
#include <hip/hip_runtime.h>
#include <hip/hip_bf16.h>
#include <cstdint>

#define LEAKY 0.2f
#define EPSF 1e-7f

// ---------------- detect edges dtype: int32 vs int64 ----------------
// Reads the first n_pairs odd 32-bit words. If edges are int64 (values
// < 2^31, non-negative), every odd word is a zero high-half -> flag stays 0.
// If int32, odd words are nbr indices (random, nonzero) -> flag = 1.
__global__ __launch_bounds__(256) void detect_kernel(const unsigned int* __restrict__ w,
                                                     int n_pairs, int* __restrict__ flag) {
    int i = blockIdx.x * 256 + threadIdx.x;
    unsigned int v = 0;
    if (i < n_pairs) v = w[2 * i + 1];
    if (__any(v != 0)) {
        if ((threadIdx.x & 63) == 0) atomicOr(flag, 1);
    }
}

// ---------------- histogram of targets ----------------
__global__ __launch_bounds__(256) void hist_kernel(const void* __restrict__ eraw,
                                                   const int* __restrict__ flag,
                                                   int* __restrict__ deg, int E) {
    int e = blockIdx.x * 256 + threadIdx.x;
    if (e >= E) return;
    int tgt;
    if (*flag) tgt = ((const int*)eraw)[2 * e];
    else       tgt = (int)((const long long*)eraw)[2 * e];
    atomicAdd(&deg[tgt], 1);
}

// ---------------- GEMM: h = X(row-major n x 128) @ W(128 x 128) ----------------
// 32-row x 128-col tile per block, 256 threads, 4x4 micro-tile per thread.
// X tile staged transposed in LDS so the k-loop reads a 4-row slice as one b128.
__global__ __launch_bounds__(256) void gemm_kernel(const float* __restrict__ X,
                                                   const float* __restrict__ W,
                                                   float* __restrict__ H, int n) {
    __shared__ float Xs[128][36];   // [k][row], pad 36 keeps b128 reads 16B-aligned
    int brow = blockIdx.x * 32;
    int t = threadIdx.x;

    // stage: coalesced float4 reads, transposed scatter into LDS
    #pragma unroll
    for (int i = 0; i < 4; ++i) {
        int idx4 = t + 256 * i;        // float4 index within 32x128 tile
        int flat = idx4 * 4;
        int r = flat >> 7;             // 0..31
        int k = flat & 127;            // multiple of 4
        int row = brow + r;
        float4 v = make_float4(0.f, 0.f, 0.f, 0.f);
        if (row < n) v = *(const float4*)(X + (size_t)row * 128 + k);
        Xs[k + 0][r] = v.x; Xs[k + 1][r] = v.y; Xs[k + 2][r] = v.z; Xs[k + 3][r] = v.w;
    }
    __syncthreads();

    int c4 = (t & 31) * 4;     // col base 0..124
    int rg = (t >> 5) * 4;     // row base 0..28
    float acc[4][4] = {{0.f}};

    #pragma unroll 4
    for (int k = 0; k < 128; ++k) {
        float4 xv = *(const float4*)(&Xs[k][rg]);
        float4 wv = *(const float4*)(W + k * 128 + c4);
        float xr[4] = {xv.x, xv.y, xv.z, xv.w};
        float wc[4] = {wv.x, wv.y, wv.z, wv.w};
        #pragma unroll
        for (int r = 0; r < 4; ++r)
            #pragma unroll
            for (int c = 0; c < 4; ++c)
                acc[r][c] += xr[r] * wc[c];
    }

    #pragma unroll
    for (int r = 0; r < 4; ++r) {
        int row = brow + rg + r;
        if (row < n) {
            float4 o = make_float4(acc[r][0], acc[r][1], acc[r][2], acc[r][3]);
            *(float4*)(H + (size_t)row * 128 + c4) = o;
        }
    }
}

// ---------------- per-node attention scalars: a = h . ka[0:128], b = h . ka[128:256] ----------------
__global__ __launch_bounds__(256) void ab_kernel(const float* __restrict__ h,
                                                 const float* __restrict__ ka,
                                                 float* __restrict__ a, float* __restrict__ b, int n) {
    int wid = threadIdx.x >> 6, lane = threadIdx.x & 63;
    int row = blockIdx.x * 4 + wid;
    if (row >= n) return;
    float2 hv = *(const float2*)(h + (size_t)row * 128 + lane * 2);
    float2 k1 = *(const float2*)(ka + lane * 2);
    float2 k2 = *(const float2*)(ka + 128 + lane * 2);
    float pa = hv.x * k1.x + hv.y * k1.y;
    float pb = hv.x * k2.x + hv.y * k2.y;
    #pragma unroll
    for (int off = 32; off; off >>= 1) {
        pa += __shfl_xor(pa, off, 64);
        pb += __shfl_xor(pb, off, 64);
    }
    if (lane == 0) { a[row] = pa; b[row] = pb; }
}

// ---------------- single-block exclusive scan over deg -> start, cursor ----------------
__global__ __launch_bounds__(1024) void scan_kernel(const int* __restrict__ deg,
                                                    int* __restrict__ start,
                                                    int* __restrict__ cursor, int n) {
    __shared__ int wsum[16];
    __shared__ int chunk_total;
    __shared__ int carry_sh;
    int t = threadIdx.x;
    if (t == 0) carry_sh = 0;
    __syncthreads();
    for (int base = 0; base < n; base += 1024) {
        int i = base + t;
        int v = (i < n) ? deg[i] : 0;
        int lane = t & 63, wid = t >> 6;
        int x = v;
        #pragma unroll
        for (int off = 1; off < 64; off <<= 1) {
            int y = __shfl_up(x, off, 64);
            if (lane >= off) x += y;
        }
        if (lane == 63) wsum[wid] = x;
        __syncthreads();
        if (t == 0) {
            int acc = 0;
            #pragma unroll
            for (int w = 0; w < 16; ++w) { int tmp = wsum[w]; wsum[w] = acc; acc += tmp; }
            chunk_total = acc;
        }
        __syncthreads();
        int excl = carry_sh + wsum[wid] + (x - v);
        if (i < n) { start[i] = excl; cursor[i] = excl; }
        __syncthreads();                 // everyone read carry_sh before t0 bumps it
        if (t == 0) carry_sh += chunk_total;
        __syncthreads();
    }
    if (t == 0) start[n] = carry_sh;
}

// ---------------- per-edge score + CSR scatter ----------------
__global__ __launch_bounds__(256) void scatter_kernel(const void* __restrict__ eraw,
                                                      const int* __restrict__ flag,
                                                      const float* __restrict__ a,
                                                      const float* __restrict__ b,
                                                      int* __restrict__ cursor,
                                                      int* __restrict__ csr_nbr,
                                                      float* __restrict__ csr_s, int E) {
    int e = blockIdx.x * 256 + threadIdx.x;
    if (e >= E) return;
    int tgt, nbr;
    if (*flag) {
        const int* e32 = (const int*)eraw;
        tgt = e32[2 * e]; nbr = e32[2 * e + 1];
    } else {
        const long long* e64 = (const long long*)eraw;
        tgt = (int)e64[2 * e]; nbr = (int)e64[2 * e + 1];
    }
    float sc = a[tgt] + b[nbr];
    sc = (sc >= 0.f) ? sc : LEAKY * sc;          // leaky_relu
    sc = fminf(fmaxf(sc, -2.f), 2.f);            // clip
    float se = expf(sc);
    int p = atomicAdd(&cursor[tgt], 1);
    csr_nbr[p] = nbr;
    csr_s[p] = se;
}

// ---------------- aggregation: one wave per node ----------------
__global__ __launch_bounds__(256) void aggregate_kernel(const float* __restrict__ h,
                                                        const int* __restrict__ start,
                                                        const int* __restrict__ csr_nbr,
                                                        const float* __restrict__ csr_s,
                                                        float* __restrict__ out, int n) {
    int wid = threadIdx.x >> 6, lane = threadIdx.x & 63;
    int v = blockIdx.x * 4 + wid;
    if (v >= n) return;
    int r0 = start[v], r1 = start[v + 1];

    // denom
    float ssum = 0.f;
    for (int r = r0 + lane; r < r1; r += 64) ssum += csr_s[r];
    #pragma unroll
    for (int off = 32; off; off >>= 1) ssum += __shfl_xor(ssum, off, 64);
    float inv = 1.f / (ssum + EPSF);

    float2 acc = make_float2(0.f, 0.f);
    for (int base = r0; base < r1; base += 64) {
        int m = min(64, r1 - base);
        int nb = 0; float sv = 0.f;
        if (lane < m) { nb = csr_nbr[base + lane]; sv = csr_s[base + lane]; }
        for (int j = 0; j < m; ++j) {
            int nbj = __shfl(nb, j, 64);
            float wj = __shfl(sv, j, 64) * inv;
            float2 hv = *(const float2*)(h + (size_t)nbj * 128 + lane * 2);
            acc.x += wj * hv.x;
            acc.y += wj * hv.y;
        }
    }
    *(float2*)(out + (size_t)v * 128 + lane * 2) = acc;
}

extern "C" void kernel_launch(void* const* d_in, const int* in_sizes, int n_in,
                              void* d_out, int out_size, void* d_ws, size_t ws_size,
                              hipStream_t stream) {
    const float* X     = (const float*)d_in[0];
    const void*  edges = d_in[1];
    const float* W     = (const float*)d_in[2];
    const float* ka    = (const float*)d_in[3];
    float* out = (float*)d_out;

    int n_nodes = in_sizes[0] / 128;
    int E       = in_sizes[1] / 2;

    char* ws = (char*)d_ws;
    size_t off = 0;
    auto alloc = [&](size_t bytes) { size_t o = off; off = (off + bytes + 255) & ~(size_t)255; return o; };
    float* h      = (float*)(ws + alloc((size_t)n_nodes * 128 * 4));
    float* a      = (float*)(ws + alloc((size_t)n_nodes * 4));
    float* b      = (float*)(ws + alloc((size_t)n_nodes * 4));
    int*   deg    = (int*)  (ws + alloc((size_t)n_nodes * 4));
    int*   start  = (int*)  (ws + alloc((size_t)(n_nodes + 1) * 4));
    int*   cursor = (int*)  (ws + alloc((size_t)n_nodes * 4));
    int*   csr_nbr= (int*)  (ws + alloc((size_t)E * 4));
    float* csr_s  = (float*)(ws + alloc((size_t)E * 4));
    int*   flag   = (int*)  (ws + alloc(4));

    hipMemsetAsync(deg, 0, (size_t)n_nodes * 4, stream);
    hipMemsetAsync(flag, 0, 4, stream);

    int eb = (E + 255) / 256;
    detect_kernel<<<eb, 256, 0, stream>>>((const unsigned int*)edges, E, flag);
    hist_kernel<<<eb, 256, 0, stream>>>(edges, flag, deg, E);
    gemm_kernel<<<(n_nodes + 31) / 32, 256, 0, stream>>>(X, W, h, n_nodes);
    ab_kernel<<<(n_nodes + 3) / 4, 256, 0, stream>>>(h, ka, a, b, n_nodes);
    scan_kernel<<<1, 1024, 0, stream>>>(deg, start, cursor, n_nodes);
    scatter_kernel<<<eb, 256, 0, stream>>>(edges, flag, a, b, cursor, csr_nbr, csr_s, E);
    aggregate_kernel<<<(n_nodes + 3) / 4, 256, 0, stream>>>(h, start, csr_nbr, csr_s, out, n_nodes);
}

// Round 2
// 211.151 us; speedup vs baseline: 1.8548x; 1.8548x over previous
//
#include <hip/hip_runtime.h>
#include <hip/hip_bf16.h>
#include <cstdint>

#define LEAKY 0.2f
#define EPSF 1e-7f

// ---------------- detect edges dtype: int32 vs int64 ----------------
// One block samples the first <=8192 pairs' odd 32-bit words. int64 edges
// (node ids < 2^31) have all-zero high halves; int32 edges have random nbr
// ids there (P(all 8192 == 0) ~ 0). Plain store — no atomic contention.
__global__ __launch_bounds__(256) void detect_kernel(const unsigned int* __restrict__ w,
                                                     int n_pairs, int* __restrict__ flag) {
    int t = threadIdx.x;
    unsigned int acc = 0;
    int lim = n_pairs < 8192 ? n_pairs : 8192;
    for (int i = t; i < lim; i += 256) acc |= w[2 * i + 1];
    if (__any(acc != 0)) {
        if ((t & 63) == 0) *flag = 1;   // benign race: all writers store 1
    }
}

// ---------------- histogram of targets ----------------
__global__ __launch_bounds__(256) void hist_kernel(const void* __restrict__ eraw,
                                                   const int* __restrict__ flag,
                                                   int* __restrict__ deg, int E) {
    int e = blockIdx.x * 256 + threadIdx.x;
    if (e >= E) return;
    int tgt;
    if (*flag) tgt = ((const int*)eraw)[2 * e];
    else       tgt = (int)((const long long*)eraw)[2 * e];
    atomicAdd(&deg[tgt], 1);
}

// ---------------- GEMM: h = X(row-major n x 128) @ W(128 x 128) ----------------
__global__ __launch_bounds__(256) void gemm_kernel(const float* __restrict__ X,
                                                   const float* __restrict__ W,
                                                   float* __restrict__ H, int n) {
    __shared__ float Xs[128][36];
    int brow = blockIdx.x * 32;
    int t = threadIdx.x;

    #pragma unroll
    for (int i = 0; i < 4; ++i) {
        int idx4 = t + 256 * i;
        int flat = idx4 * 4;
        int r = flat >> 7;
        int k = flat & 127;
        int row = brow + r;
        float4 v = make_float4(0.f, 0.f, 0.f, 0.f);
        if (row < n) v = *(const float4*)(X + (size_t)row * 128 + k);
        Xs[k + 0][r] = v.x; Xs[k + 1][r] = v.y; Xs[k + 2][r] = v.z; Xs[k + 3][r] = v.w;
    }
    __syncthreads();

    int c4 = (t & 31) * 4;
    int rg = (t >> 5) * 4;
    float acc[4][4] = {{0.f}};

    #pragma unroll 4
    for (int k = 0; k < 128; ++k) {
        float4 xv = *(const float4*)(&Xs[k][rg]);
        float4 wv = *(const float4*)(W + k * 128 + c4);
        float xr[4] = {xv.x, xv.y, xv.z, xv.w};
        float wc[4] = {wv.x, wv.y, wv.z, wv.w};
        #pragma unroll
        for (int r = 0; r < 4; ++r)
            #pragma unroll
            for (int c = 0; c < 4; ++c)
                acc[r][c] += xr[r] * wc[c];
    }

    #pragma unroll
    for (int r = 0; r < 4; ++r) {
        int row = brow + rg + r;
        if (row < n) {
            float4 o = make_float4(acc[r][0], acc[r][1], acc[r][2], acc[r][3]);
            *(float4*)(H + (size_t)row * 128 + c4) = o;
        }
    }
}

// ---------------- per-node attention scalars ----------------
__global__ __launch_bounds__(256) void ab_kernel(const float* __restrict__ h,
                                                 const float* __restrict__ ka,
                                                 float* __restrict__ a, float* __restrict__ b, int n) {
    int wid = threadIdx.x >> 6, lane = threadIdx.x & 63;
    int row = blockIdx.x * 4 + wid;
    if (row >= n) return;
    float2 hv = *(const float2*)(h + (size_t)row * 128 + lane * 2);
    float2 k1 = *(const float2*)(ka + lane * 2);
    float2 k2 = *(const float2*)(ka + 128 + lane * 2);
    float pa = hv.x * k1.x + hv.y * k1.y;
    float pb = hv.x * k2.x + hv.y * k2.y;
    #pragma unroll
    for (int off = 32; off; off >>= 1) {
        pa += __shfl_xor(pa, off, 64);
        pb += __shfl_xor(pb, off, 64);
    }
    if (lane == 0) { a[row] = pa; b[row] = pb; }
}

// ---------------- parallel scan: A) per-block sums ----------------
__global__ __launch_bounds__(1024) void blocksum_kernel(const int* __restrict__ deg,
                                                        int* __restrict__ bsum, int n) {
    __shared__ int wsum[16];
    int t = threadIdx.x, lane = t & 63, wid = t >> 6;
    int i = blockIdx.x * 1024 + t;
    int v = (i < n) ? deg[i] : 0;
    #pragma unroll
    for (int off = 32; off; off >>= 1) v += __shfl_xor(v, off, 64);
    if (lane == 0) wsum[wid] = v;
    __syncthreads();
    if (t == 0) {
        int s = 0;
        #pragma unroll
        for (int w = 0; w < 16; ++w) s += wsum[w];
        bsum[blockIdx.x] = s;
    }
}

// ---------------- B) single-block exclusive scan of block sums (nb <= 1024) ----------------
__global__ __launch_bounds__(1024) void scanb_kernel(const int* __restrict__ bsum,
                                                     int* __restrict__ boff,
                                                     int* __restrict__ start_n, int nb) {
    __shared__ int wsum[16];
    __shared__ int tot;
    int t = threadIdx.x, lane = t & 63, wid = t >> 6;
    int v = (t < nb) ? bsum[t] : 0;
    int x = v;
    #pragma unroll
    for (int off = 1; off < 64; off <<= 1) {
        int y = __shfl_up(x, off, 64);
        if (lane >= off) x += y;
    }
    if (lane == 63) wsum[wid] = x;
    __syncthreads();
    if (t == 0) {
        int acc = 0;
        #pragma unroll
        for (int w = 0; w < 16; ++w) { int tmp = wsum[w]; wsum[w] = acc; acc += tmp; }
        tot = acc;
    }
    __syncthreads();
    int excl = wsum[wid] + (x - v);
    if (t < nb) boff[t] = excl;
    if (t == 0) *start_n = tot;
}

// ---------------- C) per-block exclusive scan + block offset -> start, cursor ----------------
__global__ __launch_bounds__(1024) void scanf_kernel(const int* __restrict__ deg,
                                                     const int* __restrict__ boff,
                                                     int* __restrict__ start,
                                                     int* __restrict__ cursor, int n) {
    __shared__ int wsum[16];
    int t = threadIdx.x, lane = t & 63, wid = t >> 6;
    int i = blockIdx.x * 1024 + t;
    int v = (i < n) ? deg[i] : 0;
    int x = v;
    #pragma unroll
    for (int off = 1; off < 64; off <<= 1) {
        int y = __shfl_up(x, off, 64);
        if (lane >= off) x += y;
    }
    if (lane == 63) wsum[wid] = x;
    __syncthreads();
    if (t == 0) {
        int acc = 0;
        #pragma unroll
        for (int w = 0; w < 16; ++w) { int tmp = wsum[w]; wsum[w] = acc; acc += tmp; }
    }
    __syncthreads();
    int excl = boff[blockIdx.x] + wsum[wid] + (x - v);
    if (i < n) { start[i] = excl; cursor[i] = excl; }
}

// ---------------- per-edge score + CSR scatter ----------------
__global__ __launch_bounds__(256) void scatter_kernel(const void* __restrict__ eraw,
                                                      const int* __restrict__ flag,
                                                      const float* __restrict__ a,
                                                      const float* __restrict__ b,
                                                      int* __restrict__ cursor,
                                                      int* __restrict__ csr_nbr,
                                                      float* __restrict__ csr_s, int E) {
    int e = blockIdx.x * 256 + threadIdx.x;
    if (e >= E) return;
    int tgt, nbr;
    if (*flag) {
        const int* e32 = (const int*)eraw;
        tgt = e32[2 * e]; nbr = e32[2 * e + 1];
    } else {
        const long long* e64 = (const long long*)eraw;
        tgt = (int)e64[2 * e]; nbr = (int)e64[2 * e + 1];
    }
    float sc = a[tgt] + b[nbr];
    sc = (sc >= 0.f) ? sc : LEAKY * sc;
    sc = fminf(fmaxf(sc, -2.f), 2.f);
    float se = expf(sc);
    int p = atomicAdd(&cursor[tgt], 1);
    csr_nbr[p] = nbr;
    csr_s[p] = se;
}

// ---------------- aggregation: one wave per node ----------------
__global__ __launch_bounds__(256) void aggregate_kernel(const float* __restrict__ h,
                                                        const int* __restrict__ start,
                                                        const int* __restrict__ csr_nbr,
                                                        const float* __restrict__ csr_s,
                                                        float* __restrict__ out, int n) {
    int wid = threadIdx.x >> 6, lane = threadIdx.x & 63;
    int v = blockIdx.x * 4 + wid;
    if (v >= n) return;
    int r0 = start[v], r1 = start[v + 1];

    float ssum = 0.f;
    for (int r = r0 + lane; r < r1; r += 64) ssum += csr_s[r];
    #pragma unroll
    for (int off = 32; off; off >>= 1) ssum += __shfl_xor(ssum, off, 64);
    float inv = 1.f / (ssum + EPSF);

    float2 acc = make_float2(0.f, 0.f);
    for (int base = r0; base < r1; base += 64) {
        int m = min(64, r1 - base);
        int nb = 0; float sv = 0.f;
        if (lane < m) { nb = csr_nbr[base + lane]; sv = csr_s[base + lane]; }
        for (int j = 0; j < m; ++j) {
            int nbj = __shfl(nb, j, 64);
            float wj = __shfl(sv, j, 64) * inv;
            float2 hv = *(const float2*)(h + (size_t)nbj * 128 + lane * 2);
            acc.x += wj * hv.x;
            acc.y += wj * hv.y;
        }
    }
    *(float2*)(out + (size_t)v * 128 + lane * 2) = acc;
}

extern "C" void kernel_launch(void* const* d_in, const int* in_sizes, int n_in,
                              void* d_out, int out_size, void* d_ws, size_t ws_size,
                              hipStream_t stream) {
    const float* X     = (const float*)d_in[0];
    const void*  edges = d_in[1];
    const float* W     = (const float*)d_in[2];
    const float* ka    = (const float*)d_in[3];
    float* out = (float*)d_out;

    int n_nodes = in_sizes[0] / 128;
    int E       = in_sizes[1] / 2;
    int nb      = (n_nodes + 1023) / 1024;

    char* ws = (char*)d_ws;
    size_t off = 0;
    auto alloc = [&](size_t bytes) { size_t o = off; off = (off + bytes + 255) & ~(size_t)255; return o; };
    float* h      = (float*)(ws + alloc((size_t)n_nodes * 128 * 4));
    float* a      = (float*)(ws + alloc((size_t)n_nodes * 4));
    float* b      = (float*)(ws + alloc((size_t)n_nodes * 4));
    int*   deg    = (int*)  (ws + alloc((size_t)n_nodes * 4));
    int*   start  = (int*)  (ws + alloc((size_t)(n_nodes + 1) * 4));
    int*   cursor = (int*)  (ws + alloc((size_t)n_nodes * 4));
    int*   bsum   = (int*)  (ws + alloc((size_t)nb * 4));
    int*   boff   = (int*)  (ws + alloc((size_t)nb * 4));
    int*   csr_nbr= (int*)  (ws + alloc((size_t)E * 4));
    float* csr_s  = (float*)(ws + alloc((size_t)E * 4));
    int*   flag   = (int*)  (ws + alloc(4));

    hipMemsetAsync(deg, 0, (size_t)n_nodes * 4, stream);
    hipMemsetAsync(flag, 0, 4, stream);

    int eb = (E + 255) / 256;
    detect_kernel<<<1, 256, 0, stream>>>((const unsigned int*)edges, E, flag);
    hist_kernel<<<eb, 256, 0, stream>>>(edges, flag, deg, E);
    gemm_kernel<<<(n_nodes + 31) / 32, 256, 0, stream>>>(X, W, h, n_nodes);
    ab_kernel<<<(n_nodes + 3) / 4, 256, 0, stream>>>(h, ka, a, b, n_nodes);
    blocksum_kernel<<<nb, 1024, 0, stream>>>(deg, bsum, n_nodes);
    scanb_kernel<<<1, 1024, 0, stream>>>(bsum, boff, start + n_nodes, nb);
    scanf_kernel<<<nb, 1024, 0, stream>>>(deg, boff, start, cursor, n_nodes);
    scatter_kernel<<<eb, 256, 0, stream>>>(edges, flag, a, b, cursor, csr_nbr, csr_s, E);
    aggregate_kernel<<<(n_nodes + 3) / 4, 256, 0, stream>>>(h, start, csr_nbr, csr_s, out, n_nodes);
}

// Round 3
// 201.570 us; speedup vs baseline: 1.9429x; 1.0475x over previous
//
#include <hip/hip_runtime.h>
#include <hip/hip_bf16.h>
#include <cstdint>

#define LEAKY 0.2f
#define EPSF 1e-7f

// ---------------- detect edges dtype: int32 vs int64 (writes flag itself) --------
__global__ __launch_bounds__(256) void detect_kernel(const unsigned int* __restrict__ w,
                                                     int n_pairs, int* __restrict__ flag) {
    __shared__ int any_sh;
    int t = threadIdx.x;
    if (t == 0) any_sh = 0;
    __syncthreads();
    unsigned int acc = 0;
    int lim = n_pairs < 8192 ? n_pairs : 8192;
    for (int i = t; i < lim; i += 256) acc |= w[2 * i + 1];
    if (__any(acc != 0)) {
        if ((t & 63) == 0) any_sh = 1;
    }
    __syncthreads();
    if (t == 0) *flag = any_sh ? 1 : 0;   // int64 edges: all-zero high halves -> 0
}

// ---------------- histogram of targets ----------------
__global__ __launch_bounds__(256) void hist_kernel(const void* __restrict__ eraw,
                                                   const int* __restrict__ flag,
                                                   int* __restrict__ deg, int E) {
    int e = blockIdx.x * 256 + threadIdx.x;
    if (e >= E) return;
    int tgt;
    if (*flag) tgt = ((const int*)eraw)[2 * e];
    else       tgt = (int)((const long long*)eraw)[2 * e];
    atomicAdd(&deg[tgt], 1);
}

// ---------------- GEMM: h16 = bf16(X @ W), plus a = h.ka[0:128], b = h.ka[128:256] ----
// 32-row x 128-col tile, 256 threads, 4x4 micro-tile. a/b computed from exact f32
// accumulators (epilogue-fused), h stored bf16 to halve gather traffic downstream.
__global__ __launch_bounds__(256) void gemm_kernel(const float* __restrict__ X,
                                                   const float* __restrict__ W,
                                                   const float* __restrict__ ka,
                                                   unsigned short* __restrict__ h16,
                                                   float* __restrict__ a,
                                                   float* __restrict__ b, int n) {
    __shared__ float Xs[128][36];
    int brow = blockIdx.x * 32;
    int t = threadIdx.x;

    #pragma unroll
    for (int i = 0; i < 4; ++i) {
        int idx4 = t + 256 * i;
        int flat = idx4 * 4;
        int r = flat >> 7;
        int k = flat & 127;
        int row = brow + r;
        float4 v = make_float4(0.f, 0.f, 0.f, 0.f);
        if (row < n) v = *(const float4*)(X + (size_t)row * 128 + k);
        Xs[k + 0][r] = v.x; Xs[k + 1][r] = v.y; Xs[k + 2][r] = v.z; Xs[k + 3][r] = v.w;
    }
    __syncthreads();

    int c4 = (t & 31) * 4;
    int rg = (t >> 5) * 4;
    float acc[4][4] = {{0.f}};

    #pragma unroll 4
    for (int k = 0; k < 128; ++k) {
        float4 xv = *(const float4*)(&Xs[k][rg]);
        float4 wv = *(const float4*)(W + k * 128 + c4);
        float xr[4] = {xv.x, xv.y, xv.z, xv.w};
        float wc[4] = {wv.x, wv.y, wv.z, wv.w};
        #pragma unroll
        for (int r = 0; r < 4; ++r)
            #pragma unroll
            for (int c = 0; c < 4; ++c)
                acc[r][c] += xr[r] * wc[c];
    }

    // epilogue 1: h bf16 store (8B per row per thread)
    #pragma unroll
    for (int r = 0; r < 4; ++r) {
        int row = brow + rg + r;
        if (row < n) {
            union { unsigned short u[4]; uint2 v; } p;
            #pragma unroll
            for (int c = 0; c < 4; ++c)
                p.u[c] = __bfloat16_as_ushort(__float2bfloat16(acc[r][c]));
            *(uint2*)(h16 + (size_t)row * 128 + c4) = p.v;
        }
    }

    // epilogue 2: per-node attention scalars from exact f32 acc
    float ka1[4], ka2[4];
    #pragma unroll
    for (int i = 0; i < 4; ++i) { ka1[i] = ka[c4 + i]; ka2[i] = ka[128 + c4 + i]; }
    #pragma unroll
    for (int r = 0; r < 4; ++r) {
        float pa = acc[r][0] * ka1[0] + acc[r][1] * ka1[1] + acc[r][2] * ka1[2] + acc[r][3] * ka1[3];
        float pb = acc[r][0] * ka2[0] + acc[r][1] * ka2[1] + acc[r][2] * ka2[2] + acc[r][3] * ka2[3];
        #pragma unroll
        for (int off = 16; off; off >>= 1) {  // reduce across the 32 lanes sharing this row
            pa += __shfl_xor(pa, off, 64);
            pb += __shfl_xor(pb, off, 64);
        }
        int row = brow + rg + r;
        if ((t & 31) == 0 && row < n) { a[row] = pa; b[row] = pb; }
    }
}

// ---------------- parallel scan: A) per-block sums ----------------
__global__ __launch_bounds__(1024) void blocksum_kernel(const int* __restrict__ deg,
                                                        int* __restrict__ bsum, int n) {
    __shared__ int wsum[16];
    int t = threadIdx.x, lane = t & 63, wid = t >> 6;
    int i = blockIdx.x * 1024 + t;
    int v = (i < n) ? deg[i] : 0;
    #pragma unroll
    for (int off = 32; off; off >>= 1) v += __shfl_xor(v, off, 64);
    if (lane == 0) wsum[wid] = v;
    __syncthreads();
    if (t == 0) {
        int s = 0;
        #pragma unroll
        for (int w = 0; w < 16; ++w) s += wsum[w];
        bsum[blockIdx.x] = s;
    }
}

// ---------------- B) single-block exclusive scan of block sums (nb <= 1024) -------
__global__ __launch_bounds__(1024) void scanb_kernel(const int* __restrict__ bsum,
                                                     int* __restrict__ boff,
                                                     int* __restrict__ start_n, int nb) {
    __shared__ int wsum[16];
    __shared__ int tot;
    int t = threadIdx.x, lane = t & 63, wid = t >> 6;
    int v = (t < nb) ? bsum[t] : 0;
    int x = v;
    #pragma unroll
    for (int off = 1; off < 64; off <<= 1) {
        int y = __shfl_up(x, off, 64);
        if (lane >= off) x += y;
    }
    if (lane == 63) wsum[wid] = x;
    __syncthreads();
    if (t == 0) {
        int acc = 0;
        #pragma unroll
        for (int w = 0; w < 16; ++w) { int tmp = wsum[w]; wsum[w] = acc; acc += tmp; }
        tot = acc;
    }
    __syncthreads();
    int excl = wsum[wid] + (x - v);
    if (t < nb) boff[t] = excl;
    if (t == 0) *start_n = tot;
}

// ---------------- C) per-block exclusive scan + block offset -> start, cursor -----
__global__ __launch_bounds__(1024) void scanf_kernel(const int* __restrict__ deg,
                                                     const int* __restrict__ boff,
                                                     int* __restrict__ start,
                                                     int* __restrict__ cursor, int n) {
    __shared__ int wsum[16];
    int t = threadIdx.x, lane = t & 63, wid = t >> 6;
    int i = blockIdx.x * 1024 + t;
    int v = (i < n) ? deg[i] : 0;
    int x = v;
    #pragma unroll
    for (int off = 1; off < 64; off <<= 1) {
        int y = __shfl_up(x, off, 64);
        if (lane >= off) x += y;
    }
    if (lane == 63) wsum[wid] = x;
    __syncthreads();
    if (t == 0) {
        int acc = 0;
        #pragma unroll
        for (int w = 0; w < 16; ++w) { int tmp = wsum[w]; wsum[w] = acc; acc += tmp; }
    }
    __syncthreads();
    int excl = boff[blockIdx.x] + wsum[wid] + (x - v);
    if (i < n) { start[i] = excl; cursor[i] = excl; }
}

// ---------------- per-edge score + CSR scatter ----------------
__global__ __launch_bounds__(256) void scatter_kernel(const void* __restrict__ eraw,
                                                      const int* __restrict__ flag,
                                                      const float* __restrict__ a,
                                                      const float* __restrict__ b,
                                                      int* __restrict__ cursor,
                                                      int* __restrict__ csr_nbr,
                                                      float* __restrict__ csr_s, int E) {
    int e = blockIdx.x * 256 + threadIdx.x;
    if (e >= E) return;
    int tgt, nbr;
    if (*flag) {
        const int* e32 = (const int*)eraw;
        tgt = e32[2 * e]; nbr = e32[2 * e + 1];
    } else {
        const long long* e64 = (const long long*)eraw;
        tgt = (int)e64[2 * e]; nbr = (int)e64[2 * e + 1];
    }
    float sc = a[tgt] + b[nbr];
    sc = (sc >= 0.f) ? sc : LEAKY * sc;
    sc = fminf(fmaxf(sc, -2.f), 2.f);
    float se = expf(sc);
    int p = atomicAdd(&cursor[tgt], 1);
    csr_nbr[p] = nbr;
    csr_s[p] = se;
}

// ---------------- aggregation: one wave per node, bf16 h gather ----------------
__global__ __launch_bounds__(256) void aggregate_kernel(const unsigned short* __restrict__ h16,
                                                        const int* __restrict__ start,
                                                        const int* __restrict__ csr_nbr,
                                                        const float* __restrict__ csr_s,
                                                        float* __restrict__ out, int n) {
    int wid = threadIdx.x >> 6, lane = threadIdx.x & 63;
    int v = blockIdx.x * 4 + wid;
    if (v >= n) return;
    int r0 = start[v], r1 = start[v + 1];

    float ssum = 0.f;
    for (int r = r0 + lane; r < r1; r += 64) ssum += csr_s[r];
    #pragma unroll
    for (int off = 32; off; off >>= 1) ssum += __shfl_xor(ssum, off, 64);
    float inv = 1.f / (ssum + EPSF);

    float2 acc = make_float2(0.f, 0.f);
    for (int base = r0; base < r1; base += 64) {
        int m = min(64, r1 - base);
        int nb = 0; float sv = 0.f;
        if (lane < m) { nb = csr_nbr[base + lane]; sv = csr_s[base + lane]; }
        for (int j = 0; j < m; ++j) {
            int nbj = __shfl(nb, j, 64);
            float wj = __shfl(sv, j, 64) * inv;
            unsigned int hv = *(const unsigned int*)(h16 + (size_t)nbj * 128 + lane * 2);
            float lo = __uint_as_float(hv << 16);            // bf16 -> f32
            float hi = __uint_as_float(hv & 0xffff0000u);
            acc.x += wj * lo;
            acc.y += wj * hi;
        }
    }
    *(float2*)(out + (size_t)v * 128 + lane * 2) = acc;
}

extern "C" void kernel_launch(void* const* d_in, const int* in_sizes, int n_in,
                              void* d_out, int out_size, void* d_ws, size_t ws_size,
                              hipStream_t stream) {
    const float* X     = (const float*)d_in[0];
    const void*  edges = d_in[1];
    const float* W     = (const float*)d_in[2];
    const float* ka    = (const float*)d_in[3];
    float* out = (float*)d_out;

    int n_nodes = in_sizes[0] / 128;
    int E       = in_sizes[1] / 2;
    int nb      = (n_nodes + 1023) / 1024;

    char* ws = (char*)d_ws;
    size_t off = 0;
    auto alloc = [&](size_t bytes) { size_t o = off; off = (off + bytes + 255) & ~(size_t)255; return o; };
    unsigned short* h16 = (unsigned short*)(ws + alloc((size_t)n_nodes * 128 * 2));
    float* a      = (float*)(ws + alloc((size_t)n_nodes * 4));
    float* b      = (float*)(ws + alloc((size_t)n_nodes * 4));
    int*   deg    = (int*)  (ws + alloc((size_t)n_nodes * 4));
    int*   start  = (int*)  (ws + alloc((size_t)(n_nodes + 1) * 4));
    int*   cursor = (int*)  (ws + alloc((size_t)n_nodes * 4));
    int*   bsum   = (int*)  (ws + alloc((size_t)nb * 4));
    int*   boff   = (int*)  (ws + alloc((size_t)nb * 4));
    int*   csr_nbr= (int*)  (ws + alloc((size_t)E * 4));
    float* csr_s  = (float*)(ws + alloc((size_t)E * 4));
    int*   flag   = (int*)  (ws + alloc(4));

    hipMemsetAsync(deg, 0, (size_t)n_nodes * 4, stream);

    int eb = (E + 255) / 256;
    detect_kernel<<<1, 256, 0, stream>>>((const unsigned int*)edges, E, flag);
    hist_kernel<<<eb, 256, 0, stream>>>(edges, flag, deg, E);
    gemm_kernel<<<(n_nodes + 31) / 32, 256, 0, stream>>>(X, W, ka, h16, a, b, n_nodes);
    blocksum_kernel<<<nb, 1024, 0, stream>>>(deg, bsum, n_nodes);
    scanb_kernel<<<1, 1024, 0, stream>>>(bsum, boff, start + n_nodes, nb);
    scanf_kernel<<<nb, 1024, 0, stream>>>(deg, boff, start, cursor, n_nodes);
    scatter_kernel<<<eb, 256, 0, stream>>>(edges, flag, a, b, cursor, csr_nbr, csr_s, E);
    aggregate_kernel<<<(n_nodes + 3) / 4, 256, 0, stream>>>(h16, start, csr_nbr, csr_s, out, n_nodes);
}

// Round 4
// 193.427 us; speedup vs baseline: 2.0247x; 1.0421x over previous
//
#include <hip/hip_runtime.h>
#include <hip/hip_bf16.h>
#include <cstdint>

#define LEAKY 0.2f
#define EPSF 1e-7f

// ---------------- detect edges dtype: int32 vs int64 ----------------
__global__ __launch_bounds__(256) void detect_kernel(const unsigned int* __restrict__ w,
                                                     int n_pairs, int* __restrict__ flag) {
    __shared__ int any_sh;
    int t = threadIdx.x;
    if (t == 0) any_sh = 0;
    __syncthreads();
    unsigned int acc = 0;
    int lim = n_pairs < 8192 ? n_pairs : 8192;
    for (int i = t; i < lim; i += 256) acc |= w[2 * i + 1];
    if (__any(acc != 0)) {
        if ((t & 63) == 0) any_sh = 1;
    }
    __syncthreads();
    if (t == 0) *flag = any_sh ? 1 : 0;   // int64 edges: all-zero high halves -> 0
}

// ---------------- histogram of targets ----------------
__global__ __launch_bounds__(256) void hist_kernel(const void* __restrict__ eraw,
                                                   const int* __restrict__ flag,
                                                   int* __restrict__ deg, int E) {
    int e = blockIdx.x * 256 + threadIdx.x;
    if (e >= E) return;
    int tgt;
    if (*flag) tgt = ((const int*)eraw)[2 * e];
    else       tgt = (int)((const long long*)eraw)[2 * e];
    atomicAdd(&deg[tgt], 1);
}

// ---------------- GEMM: h16 = bf16(X @ W), a = h.ka[0:128], b = h.ka[128:256] ----
__global__ __launch_bounds__(256) void gemm_kernel(const float* __restrict__ X,
                                                   const float* __restrict__ W,
                                                   const float* __restrict__ ka,
                                                   unsigned short* __restrict__ h16,
                                                   float* __restrict__ a,
                                                   float* __restrict__ b, int n) {
    __shared__ float Xs[128][36];
    int brow = blockIdx.x * 32;
    int t = threadIdx.x;

    #pragma unroll
    for (int i = 0; i < 4; ++i) {
        int idx4 = t + 256 * i;
        int flat = idx4 * 4;
        int r = flat >> 7;
        int k = flat & 127;
        int row = brow + r;
        float4 v = make_float4(0.f, 0.f, 0.f, 0.f);
        if (row < n) v = *(const float4*)(X + (size_t)row * 128 + k);
        Xs[k + 0][r] = v.x; Xs[k + 1][r] = v.y; Xs[k + 2][r] = v.z; Xs[k + 3][r] = v.w;
    }
    __syncthreads();

    int c4 = (t & 31) * 4;
    int rg = (t >> 5) * 4;
    float acc[4][4] = {{0.f}};

    #pragma unroll 4
    for (int k = 0; k < 128; ++k) {
        float4 xv = *(const float4*)(&Xs[k][rg]);
        float4 wv = *(const float4*)(W + k * 128 + c4);
        float xr[4] = {xv.x, xv.y, xv.z, xv.w};
        float wc[4] = {wv.x, wv.y, wv.z, wv.w};
        #pragma unroll
        for (int r = 0; r < 4; ++r)
            #pragma unroll
            for (int c = 0; c < 4; ++c)
                acc[r][c] += xr[r] * wc[c];
    }

    #pragma unroll
    for (int r = 0; r < 4; ++r) {
        int row = brow + rg + r;
        if (row < n) {
            union { unsigned short u[4]; uint2 v; } p;
            #pragma unroll
            for (int c = 0; c < 4; ++c)
                p.u[c] = __bfloat16_as_ushort(__float2bfloat16(acc[r][c]));
            *(uint2*)(h16 + (size_t)row * 128 + c4) = p.v;
        }
    }

    float ka1[4], ka2[4];
    #pragma unroll
    for (int i = 0; i < 4; ++i) { ka1[i] = ka[c4 + i]; ka2[i] = ka[128 + c4 + i]; }
    #pragma unroll
    for (int r = 0; r < 4; ++r) {
        float pa = acc[r][0] * ka1[0] + acc[r][1] * ka1[1] + acc[r][2] * ka1[2] + acc[r][3] * ka1[3];
        float pb = acc[r][0] * ka2[0] + acc[r][1] * ka2[1] + acc[r][2] * ka2[2] + acc[r][3] * ka2[3];
        #pragma unroll
        for (int off = 16; off; off >>= 1) {
            pa += __shfl_xor(pa, off, 64);
            pb += __shfl_xor(pb, off, 64);
        }
        int row = brow + rg + r;
        if ((t & 31) == 0 && row < n) { a[row] = pa; b[row] = pb; }
    }
}

// ---------------- parallel scan: A) per-block sums ----------------
__global__ __launch_bounds__(1024) void blocksum_kernel(const int* __restrict__ deg,
                                                        int* __restrict__ bsum, int n) {
    __shared__ int wsum[16];
    int t = threadIdx.x, lane = t & 63, wid = t >> 6;
    int i = blockIdx.x * 1024 + t;
    int v = (i < n) ? deg[i] : 0;
    #pragma unroll
    for (int off = 32; off; off >>= 1) v += __shfl_xor(v, off, 64);
    if (lane == 0) wsum[wid] = v;
    __syncthreads();
    if (t == 0) {
        int s = 0;
        #pragma unroll
        for (int w = 0; w < 16; ++w) s += wsum[w];
        bsum[blockIdx.x] = s;
    }
}

// ---------------- B) single-block exclusive scan of block sums (nb <= 1024) -------
__global__ __launch_bounds__(1024) void scanb_kernel(const int* __restrict__ bsum,
                                                     int* __restrict__ boff,
                                                     int* __restrict__ start_n, int nb) {
    __shared__ int wsum[16];
    __shared__ int tot;
    int t = threadIdx.x, lane = t & 63, wid = t >> 6;
    int v = (t < nb) ? bsum[t] : 0;
    int x = v;
    #pragma unroll
    for (int off = 1; off < 64; off <<= 1) {
        int y = __shfl_up(x, off, 64);
        if (lane >= off) x += y;
    }
    if (lane == 63) wsum[wid] = x;
    __syncthreads();
    if (t == 0) {
        int acc = 0;
        #pragma unroll
        for (int w = 0; w < 16; ++w) { int tmp = wsum[w]; wsum[w] = acc; acc += tmp; }
        tot = acc;
    }
    __syncthreads();
    int excl = wsum[wid] + (x - v);
    if (t < nb) boff[t] = excl;
    if (t == 0) *start_n = tot;
}

// ---------------- C) per-block exclusive scan + block offset -> start, cursor -----
__global__ __launch_bounds__(1024) void scanf_kernel(const int* __restrict__ deg,
                                                     const int* __restrict__ boff,
                                                     int* __restrict__ start,
                                                     int* __restrict__ cursor, int n) {
    __shared__ int wsum[16];
    int t = threadIdx.x, lane = t & 63, wid = t >> 6;
    int i = blockIdx.x * 1024 + t;
    int v = (i < n) ? deg[i] : 0;
    int x = v;
    #pragma unroll
    for (int off = 1; off < 64; off <<= 1) {
        int y = __shfl_up(x, off, 64);
        if (lane >= off) x += y;
    }
    if (lane == 63) wsum[wid] = x;
    __syncthreads();
    if (t == 0) {
        int acc = 0;
        #pragma unroll
        for (int w = 0; w < 16; ++w) { int tmp = wsum[w]; wsum[w] = acc; acc += tmp; }
    }
    __syncthreads();
    int excl = boff[blockIdx.x] + wsum[wid] + (x - v);
    if (i < n) { start[i] = excl; cursor[i] = excl; }
}

// ---------------- CSR scatter: index only, minimal scattered payload ----------------
template<typename IdxT>
__global__ __launch_bounds__(256) void scatter_kernel(const void* __restrict__ eraw,
                                                      const int* __restrict__ flag,
                                                      int* __restrict__ cursor,
                                                      IdxT* __restrict__ csr, int E) {
    int e = blockIdx.x * 256 + threadIdx.x;
    if (e >= E) return;
    int tgt, nbr;
    if (*flag) {
        const int* e32 = (const int*)eraw;
        tgt = e32[2 * e]; nbr = e32[2 * e + 1];
    } else {
        const long long* e64 = (const long long*)eraw;
        tgt = (int)e64[2 * e]; nbr = (int)e64[2 * e + 1];
    }
    int p = atomicAdd(&cursor[tgt], 1);
    csr[p] = (IdxT)nbr;
}

// ---------------- aggregation: single pass, scores recomputed, post-normalize ------
// out[v] = (sum_e score_e * h[nbr_e]) / (sum_e score_e + EPS)
template<typename IdxT>
__global__ __launch_bounds__(256) void aggregate_kernel(const unsigned short* __restrict__ h16,
                                                        const float* __restrict__ a,
                                                        const float* __restrict__ b,
                                                        const int* __restrict__ start,
                                                        const IdxT* __restrict__ csr,
                                                        float* __restrict__ out, int n) {
    int wid = threadIdx.x >> 6, lane = threadIdx.x & 63;
    int v = blockIdx.x * 4 + wid;
    if (v >= n) return;
    int r0 = start[v], r1 = start[v + 1];
    float av = a[v];

    float ssum = 0.f;
    float2 acc = make_float2(0.f, 0.f);
    for (int base = r0; base < r1; base += 64) {
        int m = min(64, r1 - base);
        int nb = 0; float sv = 0.f;
        if (lane < m) {
            nb = (int)csr[base + lane];
            float sc = av + b[nb];
            sc = (sc >= 0.f) ? sc : LEAKY * sc;     // leaky_relu
            sc = fminf(fmaxf(sc, -2.f), 2.f);       // clip
            sv = __expf(sc) ;
        }
        ssum += sv;
        for (int j = 0; j < m; ++j) {
            int nbj = __shfl(nb, j, 64);
            float wj = __shfl(sv, j, 64);
            unsigned int hv = *(const unsigned int*)(h16 + (size_t)nbj * 128 + lane * 2);
            float lo = __uint_as_float(hv << 16);
            float hi = __uint_as_float(hv & 0xffff0000u);
            acc.x += wj * lo;
            acc.y += wj * hi;
        }
    }
    #pragma unroll
    for (int off = 32; off; off >>= 1) ssum += __shfl_xor(ssum, off, 64);
    float inv = 1.f / (ssum + EPSF);
    float2 o = make_float2(acc.x * inv, acc.y * inv);
    *(float2*)(out + (size_t)v * 128 + lane * 2) = o;
}

extern "C" void kernel_launch(void* const* d_in, const int* in_sizes, int n_in,
                              void* d_out, int out_size, void* d_ws, size_t ws_size,
                              hipStream_t stream) {
    const float* X     = (const float*)d_in[0];
    const void*  edges = d_in[1];
    const float* W     = (const float*)d_in[2];
    const float* ka    = (const float*)d_in[3];
    float* out = (float*)d_out;

    int n_nodes = in_sizes[0] / 128;
    int E       = in_sizes[1] / 2;
    int nb      = (n_nodes + 1023) / 1024;

    char* ws = (char*)d_ws;
    size_t off = 0;
    auto alloc = [&](size_t bytes) { size_t o = off; off = (off + bytes + 255) & ~(size_t)255; return o; };
    unsigned short* h16 = (unsigned short*)(ws + alloc((size_t)n_nodes * 128 * 2));
    float* a      = (float*)(ws + alloc((size_t)n_nodes * 4));
    float* b      = (float*)(ws + alloc((size_t)n_nodes * 4));
    int*   deg    = (int*)  (ws + alloc((size_t)n_nodes * 4));
    int*   start  = (int*)  (ws + alloc((size_t)(n_nodes + 1) * 4));
    int*   cursor = (int*)  (ws + alloc((size_t)n_nodes * 4));
    int*   bsum   = (int*)  (ws + alloc((size_t)nb * 4));
    int*   boff   = (int*)  (ws + alloc((size_t)nb * 4));
    void*  csr    = (void*) (ws + alloc((size_t)E * 4));   // u16 path uses first E*2 bytes
    int*   flag   = (int*)  (ws + alloc(4));

    hipMemsetAsync(deg, 0, (size_t)n_nodes * 4, stream);

    int eb = (E + 255) / 256;
    detect_kernel<<<1, 256, 0, stream>>>((const unsigned int*)edges, E, flag);
    hist_kernel<<<eb, 256, 0, stream>>>(edges, flag, deg, E);
    gemm_kernel<<<(n_nodes + 31) / 32, 256, 0, stream>>>(X, W, ka, h16, a, b, n_nodes);
    blocksum_kernel<<<nb, 1024, 0, stream>>>(deg, bsum, n_nodes);
    scanb_kernel<<<1, 1024, 0, stream>>>(bsum, boff, start + n_nodes, nb);
    scanf_kernel<<<nb, 1024, 0, stream>>>(deg, boff, start, cursor, n_nodes);

    int ab = (n_nodes + 3) / 4;
    if (n_nodes <= 65536) {
        scatter_kernel<unsigned short><<<eb, 256, 0, stream>>>(edges, flag, cursor, (unsigned short*)csr, E);
        aggregate_kernel<unsigned short><<<ab, 256, 0, stream>>>(h16, a, b, start, (const unsigned short*)csr, out, n_nodes);
    } else {
        scatter_kernel<unsigned int><<<eb, 256, 0, stream>>>(edges, flag, cursor, (unsigned int*)csr, E);
        aggregate_kernel<unsigned int><<<ab, 256, 0, stream>>>(h16, a, b, start, (const unsigned int*)csr, out, n_nodes);
    }
}

// Round 5
// 121.905 us; speedup vs baseline: 3.2127x; 1.5867x over previous
//
#include <hip/hip_runtime.h>
#include <hip/hip_bf16.h>
#include <cstdint>

#define LEAKY 0.2f
#define EPSF 1e-7f
#define CAP 64   // bucket capacity; deg ~ Poisson(16), P(deg>64) ~ 1e-20/node

// ---------------- K1: cursor init (cursor[v] = v*CAP) + edge dtype detect ---------
__global__ __launch_bounds__(256) void init_detect_kernel(const unsigned int* __restrict__ w,
                                                          int n_pairs, int n,
                                                          int* __restrict__ cursor,
                                                          int* __restrict__ flag) {
    int i = blockIdx.x * 256 + threadIdx.x;
    if (i < n) cursor[i] = i * CAP;
    if (blockIdx.x == 0) {
        __shared__ int any_sh;
        int t = threadIdx.x;
        if (t == 0) any_sh = 0;
        __syncthreads();
        unsigned int acc = 0;
        int lim = n_pairs < 8192 ? n_pairs : 8192;
        for (int k = t; k < lim; k += 256) acc |= w[2 * k + 1];
        if (__any(acc != 0)) {
            if ((t & 63) == 0) any_sh = 1;
        }
        __syncthreads();
        if (t == 0) *flag = any_sh ? 1 : 0;   // int64 edges: zero high halves -> 0
    }
}

// ---------------- K2: fused GEMM (blocks [0,gb)) + CSR bucket scatter (rest) -------
// GEMM: h16 = bf16(X @ W); a = h.ka[:128], b = h.ka[128:] from exact f32 acc.
// Scatter: bucket[atomic cursor[tgt]++] = nbr  (2B payload, fixed-stride buckets).
template<typename IdxT>
__global__ __launch_bounds__(256) void gemm_scatter_kernel(const float* __restrict__ X,
                                                           const float* __restrict__ W,
                                                           const float* __restrict__ ka,
                                                           unsigned short* __restrict__ h16,
                                                           float* __restrict__ a,
                                                           float* __restrict__ b, int n,
                                                           const void* __restrict__ eraw,
                                                           const int* __restrict__ flag,
                                                           int* __restrict__ cursor,
                                                           IdxT* __restrict__ bucket, int E,
                                                           int gemm_blocks) {
    if ((int)blockIdx.x >= gemm_blocks) {
        // ---- scatter path ----
        int e = ((int)blockIdx.x - gemm_blocks) * 256 + threadIdx.x;
        if (e >= E) return;
        int tgt, nbr;
        if (*flag) {
            const int* e32 = (const int*)eraw;
            tgt = e32[2 * e]; nbr = e32[2 * e + 1];
        } else {
            const long long* e64 = (const long long*)eraw;
            tgt = (int)e64[2 * e]; nbr = (int)e64[2 * e + 1];
        }
        int p = atomicAdd(&cursor[tgt], 1);
        if (p < tgt * CAP + CAP) bucket[p] = (IdxT)nbr;   // overflow guard (never fires)
        return;
    }

    // ---- gemm path ----
    __shared__ float Xs[128][36];
    int brow = blockIdx.x * 32;
    int t = threadIdx.x;

    #pragma unroll
    for (int i = 0; i < 4; ++i) {
        int idx4 = t + 256 * i;
        int flat = idx4 * 4;
        int r = flat >> 7;
        int k = flat & 127;
        int row = brow + r;
        float4 v = make_float4(0.f, 0.f, 0.f, 0.f);
        if (row < n) v = *(const float4*)(X + (size_t)row * 128 + k);
        Xs[k + 0][r] = v.x; Xs[k + 1][r] = v.y; Xs[k + 2][r] = v.z; Xs[k + 3][r] = v.w;
    }
    __syncthreads();

    int c4 = (t & 31) * 4;
    int rg = (t >> 5) * 4;
    float acc[4][4] = {{0.f}};

    #pragma unroll 4
    for (int k = 0; k < 128; ++k) {
        float4 xv = *(const float4*)(&Xs[k][rg]);
        float4 wv = *(const float4*)(W + k * 128 + c4);
        float xr[4] = {xv.x, xv.y, xv.z, xv.w};
        float wc[4] = {wv.x, wv.y, wv.z, wv.w};
        #pragma unroll
        for (int r = 0; r < 4; ++r)
            #pragma unroll
            for (int c = 0; c < 4; ++c)
                acc[r][c] += xr[r] * wc[c];
    }

    #pragma unroll
    for (int r = 0; r < 4; ++r) {
        int row = brow + rg + r;
        if (row < n) {
            union { unsigned short u[4]; uint2 v; } p;
            #pragma unroll
            for (int c = 0; c < 4; ++c)
                p.u[c] = __bfloat16_as_ushort(__float2bfloat16(acc[r][c]));
            *(uint2*)(h16 + (size_t)row * 128 + c4) = p.v;
        }
    }

    float ka1[4], ka2[4];
    #pragma unroll
    for (int i = 0; i < 4; ++i) { ka1[i] = ka[c4 + i]; ka2[i] = ka[128 + c4 + i]; }
    #pragma unroll
    for (int r = 0; r < 4; ++r) {
        float pa = acc[r][0] * ka1[0] + acc[r][1] * ka1[1] + acc[r][2] * ka1[2] + acc[r][3] * ka1[3];
        float pb = acc[r][0] * ka2[0] + acc[r][1] * ka2[1] + acc[r][2] * ka2[2] + acc[r][3] * ka2[3];
        #pragma unroll
        for (int off = 16; off; off >>= 1) {
            pa += __shfl_xor(pa, off, 64);
            pb += __shfl_xor(pb, off, 64);
        }
        int row = brow + rg + r;
        if ((t & 31) == 0 && row < n) { a[row] = pa; b[row] = pb; }
    }
}

// ---------------- K3: aggregation — quarter-wave per edge, uint4 gathers ----------
// out[v] = (sum_e score_e * h[nbr_e]) / (sum_e score_e + EPS), score recomputed.
template<typename IdxT>
__global__ __launch_bounds__(256) void aggregate_kernel(const unsigned short* __restrict__ h16,
                                                        const float* __restrict__ a,
                                                        const float* __restrict__ b,
                                                        const int* __restrict__ cursor,
                                                        const IdxT* __restrict__ bucket,
                                                        float* __restrict__ out, int n) {
    int wid = threadIdx.x >> 6, lane = threadIdx.x & 63;
    int v = blockIdx.x * 4 + wid;
    if (v >= n) return;
    int r0 = v * CAP;
    int d = cursor[v] - r0;
    d = d < CAP ? d : CAP;
    float av = a[v];
    int sub = lane >> 4;        // quarter 0..3: which edge of the group of 4
    int l16 = lane & 15;        // 16 lanes x 8 cols = 128 cols

    float ssum = 0.f;
    float acc[8];
    #pragma unroll
    for (int i = 0; i < 8; ++i) acc[i] = 0.f;

    for (int base = 0; base < d; base += 64) {
        int m = min(64, d - base);
        int nb = 0; float sv = 0.f;
        if (lane < m) {
            nb = (int)bucket[r0 + base + lane];
            float sc = av + b[nb];
            sc = (sc >= 0.f) ? sc : LEAKY * sc;     // leaky_relu
            sc = fminf(fmaxf(sc, -2.f), 2.f);       // clip
            sv = __expf(sc);
        }
        ssum += sv;
        for (int j4 = 0; j4 < m; j4 += 4) {
            int j = j4 + sub;
            if (j > 63) j = 63;              // tail: lane j>=m has sv=0 -> wj=0
            int nbj = __shfl(nb, j, 64);
            float wj = __shfl(sv, j, 64);
            uint4 hv = *(const uint4*)(h16 + (size_t)nbj * 128 + l16 * 8);
            acc[0] += wj * __uint_as_float(hv.x << 16);
            acc[1] += wj * __uint_as_float(hv.x & 0xffff0000u);
            acc[2] += wj * __uint_as_float(hv.y << 16);
            acc[3] += wj * __uint_as_float(hv.y & 0xffff0000u);
            acc[4] += wj * __uint_as_float(hv.z << 16);
            acc[5] += wj * __uint_as_float(hv.z & 0xffff0000u);
            acc[6] += wj * __uint_as_float(hv.w << 16);
            acc[7] += wj * __uint_as_float(hv.w & 0xffff0000u);
        }
    }

    #pragma unroll
    for (int off = 32; off; off >>= 1) ssum += __shfl_xor(ssum, off, 64);
    #pragma unroll
    for (int i = 0; i < 8; ++i) {
        acc[i] += __shfl_xor(acc[i], 16, 64);
        acc[i] += __shfl_xor(acc[i], 32, 64);
    }
    float inv = 1.f / (ssum + EPSF);
    // static-index select of this quarter's two columns (avoid scratch spill)
    float o0 = (sub == 0) ? acc[0] : (sub == 1) ? acc[2] : (sub == 2) ? acc[4] : acc[6];
    float o1 = (sub == 0) ? acc[1] : (sub == 1) ? acc[3] : (sub == 2) ? acc[5] : acc[7];
    float2 o = make_float2(o0 * inv, o1 * inv);
    *(float2*)(out + (size_t)v * 128 + l16 * 8 + sub * 2) = o;
}

extern "C" void kernel_launch(void* const* d_in, const int* in_sizes, int n_in,
                              void* d_out, int out_size, void* d_ws, size_t ws_size,
                              hipStream_t stream) {
    const float* X     = (const float*)d_in[0];
    const void*  edges = d_in[1];
    const float* W     = (const float*)d_in[2];
    const float* ka    = (const float*)d_in[3];
    float* out = (float*)d_out;

    int n_nodes = in_sizes[0] / 128;
    int E       = in_sizes[1] / 2;

    char* ws = (char*)d_ws;
    size_t off = 0;
    auto alloc = [&](size_t bytes) { size_t o = off; off = (off + bytes + 255) & ~(size_t)255; return o; };
    unsigned short* h16 = (unsigned short*)(ws + alloc((size_t)n_nodes * 128 * 2));
    float* a      = (float*)(ws + alloc((size_t)n_nodes * 4));
    float* b      = (float*)(ws + alloc((size_t)n_nodes * 4));
    int*   cursor = (int*)  (ws + alloc((size_t)n_nodes * 4));
    void*  bucket = (void*) (ws + alloc((size_t)n_nodes * CAP * 4)); // u16 path uses half
    int*   flag   = (int*)  (ws + alloc(4));

    int ib = (n_nodes + 255) / 256;
    int gb = (n_nodes + 31) / 32;
    int eb = (E + 255) / 256;
    int ab = (n_nodes + 3) / 4;

    init_detect_kernel<<<ib, 256, 0, stream>>>((const unsigned int*)edges, E, n_nodes, cursor, flag);

    if (n_nodes <= 65536) {
        gemm_scatter_kernel<unsigned short><<<gb + eb, 256, 0, stream>>>(
            X, W, ka, h16, a, b, n_nodes, edges, flag, cursor, (unsigned short*)bucket, E, gb);
        aggregate_kernel<unsigned short><<<ab, 256, 0, stream>>>(
            h16, a, b, cursor, (const unsigned short*)bucket, out, n_nodes);
    } else {
        gemm_scatter_kernel<unsigned int><<<gb + eb, 256, 0, stream>>>(
            X, W, ka, h16, a, b, n_nodes, edges, flag, cursor, (unsigned int*)bucket, E, gb);
        aggregate_kernel<unsigned int><<<ab, 256, 0, stream>>>(
            h16, a, b, cursor, (const unsigned int*)bucket, out, n_nodes);
    }
}

// Round 6
// 112.221 us; speedup vs baseline: 3.4899x; 1.0863x over previous
//
#include <hip/hip_runtime.h>
#include <hip/hip_bf16.h>
#include <cstdint>

#define LEAKY 0.2f
#define EPSF 1e-7f
#define CAP 64     // bucket capacity; deg ~ Poisson(16), P(deg>64) ~ 1e-20/node
#define EILP 8     // edges per scatter thread

// ---------------- K1: cursor init (cursor[v] = v*CAP) + edge dtype detect ---------
__global__ __launch_bounds__(256) void init_detect_kernel(const unsigned int* __restrict__ w,
                                                          int n_pairs, int n,
                                                          int* __restrict__ cursor,
                                                          int* __restrict__ flag) {
    int i = blockIdx.x * 256 + threadIdx.x;
    if (i < n) cursor[i] = i * CAP;
    if (blockIdx.x == 0) {
        __shared__ int any_sh;
        int t = threadIdx.x;
        if (t == 0) any_sh = 0;
        __syncthreads();
        unsigned int acc = 0;
        int lim = n_pairs < 8192 ? n_pairs : 8192;
        for (int k = t; k < lim; k += 256) acc |= w[2 * k + 1];
        if (__any(acc != 0)) {
            if ((t & 63) == 0) any_sh = 1;
        }
        __syncthreads();
        if (t == 0) *flag = any_sh ? 1 : 0;   // int64 edges: zero high halves -> 0
    }
}

// ---------------- K2: fused GEMM (blocks [0,gb)) + ILP-8 bucket scatter (rest) -----
template<typename IdxT>
__global__ __launch_bounds__(256) void gemm_scatter_kernel(const float* __restrict__ X,
                                                           const float* __restrict__ W,
                                                           const float* __restrict__ ka,
                                                           unsigned short* __restrict__ h16,
                                                           float* __restrict__ a,
                                                           float* __restrict__ b, int n,
                                                           const void* __restrict__ eraw,
                                                           const int* __restrict__ flag,
                                                           int* __restrict__ cursor,
                                                           IdxT* __restrict__ bucket, int E,
                                                           int gemm_blocks, int scat_threads) {
    if ((int)blockIdx.x >= gemm_blocks) {
        // ---- scatter path: 8 edges/thread, strided (each load coalesced) ----
        int tid = ((int)blockIdx.x - gemm_blocks) * 256 + threadIdx.x;
        bool e32 = (*flag != 0);
        int tgts[EILP], nbrs[EILP];
        #pragma unroll
        for (int k = 0; k < EILP; ++k) {
            int e = tid + k * scat_threads;
            tgts[k] = -1;
            if (e < E) {
                if (e32) {
                    uint2 p = ((const uint2*)eraw)[e];
                    tgts[k] = (int)p.x; nbrs[k] = (int)p.y;
                } else {
                    uint4 p = ((const uint4*)eraw)[e];   // int64 pair: lows at x,z
                    tgts[k] = (int)p.x; nbrs[k] = (int)p.z;
                }
            }
        }
        int slot[EILP];
        #pragma unroll
        for (int k = 0; k < EILP; ++k)
            if (tgts[k] >= 0) slot[k] = atomicAdd(&cursor[tgts[k]], 1);  // 8 in flight
        #pragma unroll
        for (int k = 0; k < EILP; ++k)
            if (tgts[k] >= 0 && slot[k] < tgts[k] * CAP + CAP)           // guard never fires
                bucket[slot[k]] = (IdxT)nbrs[k];
        return;
    }

    // ---- gemm path ----
    __shared__ float Xs[128][36];
    int brow = blockIdx.x * 32;
    int t = threadIdx.x;

    #pragma unroll
    for (int i = 0; i < 4; ++i) {
        int idx4 = t + 256 * i;
        int flat = idx4 * 4;
        int r = flat >> 7;
        int k = flat & 127;
        int row = brow + r;
        float4 v = make_float4(0.f, 0.f, 0.f, 0.f);
        if (row < n) v = *(const float4*)(X + (size_t)row * 128 + k);
        Xs[k + 0][r] = v.x; Xs[k + 1][r] = v.y; Xs[k + 2][r] = v.z; Xs[k + 3][r] = v.w;
    }
    __syncthreads();

    int c4 = (t & 31) * 4;
    int rg = (t >> 5) * 4;
    float acc[4][4] = {{0.f}};

    #pragma unroll 4
    for (int k = 0; k < 128; ++k) {
        float4 xv = *(const float4*)(&Xs[k][rg]);
        float4 wv = *(const float4*)(W + k * 128 + c4);
        float xr[4] = {xv.x, xv.y, xv.z, xv.w};
        float wc[4] = {wv.x, wv.y, wv.z, wv.w};
        #pragma unroll
        for (int r = 0; r < 4; ++r)
            #pragma unroll
            for (int c = 0; c < 4; ++c)
                acc[r][c] += xr[r] * wc[c];
    }

    #pragma unroll
    for (int r = 0; r < 4; ++r) {
        int row = brow + rg + r;
        if (row < n) {
            union { unsigned short u[4]; uint2 v; } p;
            #pragma unroll
            for (int c = 0; c < 4; ++c)
                p.u[c] = __bfloat16_as_ushort(__float2bfloat16(acc[r][c]));
            *(uint2*)(h16 + (size_t)row * 128 + c4) = p.v;
        }
    }

    float ka1[4], ka2[4];
    #pragma unroll
    for (int i = 0; i < 4; ++i) { ka1[i] = ka[c4 + i]; ka2[i] = ka[128 + c4 + i]; }
    #pragma unroll
    for (int r = 0; r < 4; ++r) {
        float pa = acc[r][0] * ka1[0] + acc[r][1] * ka1[1] + acc[r][2] * ka1[2] + acc[r][3] * ka1[3];
        float pb = acc[r][0] * ka2[0] + acc[r][1] * ka2[1] + acc[r][2] * ka2[2] + acc[r][3] * ka2[3];
        #pragma unroll
        for (int off = 16; off; off >>= 1) {
            pa += __shfl_xor(pa, off, 64);
            pb += __shfl_xor(pb, off, 64);
        }
        int row = brow + rg + r;
        if ((t & 31) == 0 && row < n) { a[row] = pa; b[row] = pb; }
    }
}

// ---------------- K3: aggregation — quarter-wave per edge, uint4 gathers ----------
template<typename IdxT>
__global__ __launch_bounds__(256) void aggregate_kernel(const unsigned short* __restrict__ h16,
                                                        const float* __restrict__ a,
                                                        const float* __restrict__ b,
                                                        const int* __restrict__ cursor,
                                                        const IdxT* __restrict__ bucket,
                                                        float* __restrict__ out, int n) {
    int wid = threadIdx.x >> 6, lane = threadIdx.x & 63;
    int v = blockIdx.x * 4 + wid;
    if (v >= n) return;
    int r0 = v * CAP;
    int d = cursor[v] - r0;
    d = d < CAP ? d : CAP;
    float av = a[v];
    int sub = lane >> 4;
    int l16 = lane & 15;

    float ssum = 0.f;
    float acc[8];
    #pragma unroll
    for (int i = 0; i < 8; ++i) acc[i] = 0.f;

    for (int base = 0; base < d; base += 64) {
        int m = min(64, d - base);
        int nb = 0; float sv = 0.f;
        if (lane < m) {
            nb = (int)bucket[r0 + base + lane];
            float sc = av + b[nb];
            sc = (sc >= 0.f) ? sc : LEAKY * sc;
            sc = fminf(fmaxf(sc, -2.f), 2.f);
            sv = __expf(sc);
        }
        ssum += sv;
        for (int j4 = 0; j4 < m; j4 += 4) {
            int j = j4 + sub;
            int nbj = __shfl(nb, j, 64);
            float wj = __shfl(sv, j, 64);
            uint4 hv = *(const uint4*)(h16 + (size_t)nbj * 128 + l16 * 8);
            acc[0] += wj * __uint_as_float(hv.x << 16);
            acc[1] += wj * __uint_as_float(hv.x & 0xffff0000u);
            acc[2] += wj * __uint_as_float(hv.y << 16);
            acc[3] += wj * __uint_as_float(hv.y & 0xffff0000u);
            acc[4] += wj * __uint_as_float(hv.z << 16);
            acc[5] += wj * __uint_as_float(hv.z & 0xffff0000u);
            acc[6] += wj * __uint_as_float(hv.w << 16);
            acc[7] += wj * __uint_as_float(hv.w & 0xffff0000u);
        }
    }

    #pragma unroll
    for (int off = 32; off; off >>= 1) ssum += __shfl_xor(ssum, off, 64);
    #pragma unroll
    for (int i = 0; i < 8; ++i) {
        acc[i] += __shfl_xor(acc[i], 16, 64);
        acc[i] += __shfl_xor(acc[i], 32, 64);
    }
    float inv = 1.f / (ssum + EPSF);
    float o0 = (sub == 0) ? acc[0] : (sub == 1) ? acc[2] : (sub == 2) ? acc[4] : acc[6];
    float o1 = (sub == 0) ? acc[1] : (sub == 1) ? acc[3] : (sub == 2) ? acc[5] : acc[7];
    float2 o = make_float2(o0 * inv, o1 * inv);
    *(float2*)(out + (size_t)v * 128 + l16 * 8 + sub * 2) = o;
}

extern "C" void kernel_launch(void* const* d_in, const int* in_sizes, int n_in,
                              void* d_out, int out_size, void* d_ws, size_t ws_size,
                              hipStream_t stream) {
    const float* X     = (const float*)d_in[0];
    const void*  edges = d_in[1];
    const float* W     = (const float*)d_in[2];
    const float* ka    = (const float*)d_in[3];
    float* out = (float*)d_out;

    int n_nodes = in_sizes[0] / 128;
    int E       = in_sizes[1] / 2;

    char* ws = (char*)d_ws;
    size_t off = 0;
    auto alloc = [&](size_t bytes) { size_t o = off; off = (off + bytes + 255) & ~(size_t)255; return o; };
    unsigned short* h16 = (unsigned short*)(ws + alloc((size_t)n_nodes * 128 * 2));
    float* a      = (float*)(ws + alloc((size_t)n_nodes * 4));
    float* b      = (float*)(ws + alloc((size_t)n_nodes * 4));
    int*   cursor = (int*)  (ws + alloc((size_t)n_nodes * 4));
    void*  bucket = (void*) (ws + alloc((size_t)n_nodes * CAP * 4)); // u16 path uses half
    int*   flag   = (int*)  (ws + alloc(4));

    int ib = (n_nodes + 255) / 256;
    int gb = (n_nodes + 31) / 32;
    int sb = (E + EILP * 256 - 1) / (EILP * 256);
    int st = sb * 256;
    int ab = (n_nodes + 3) / 4;

    init_detect_kernel<<<ib, 256, 0, stream>>>((const unsigned int*)edges, E, n_nodes, cursor, flag);

    if (n_nodes <= 65536) {
        gemm_scatter_kernel<unsigned short><<<gb + sb, 256, 0, stream>>>(
            X, W, ka, h16, a, b, n_nodes, edges, flag, cursor, (unsigned short*)bucket, E, gb, st);
        aggregate_kernel<unsigned short><<<ab, 256, 0, stream>>>(
            h16, a, b, cursor, (const unsigned short*)bucket, out, n_nodes);
    } else {
        gemm_scatter_kernel<unsigned int><<<gb + sb, 256, 0, stream>>>(
            X, W, ka, h16, a, b, n_nodes, edges, flag, cursor, (unsigned int*)bucket, E, gb, st);
        aggregate_kernel<unsigned int><<<ab, 256, 0, stream>>>(
            h16, a, b, cursor, (const unsigned int*)bucket, out, n_nodes);
    }
}

// Round 7
// 107.401 us; speedup vs baseline: 3.6465x; 1.0449x over previous
//
#include <hip/hip_runtime.h>
#include <hip/hip_bf16.h>
#include <cstdint>

#define LEAKY 0.2f
#define EPSF 1e-7f
#define NPART 8    // scatter partitions, aligned to XCD round-robin of blockIdx
#define CAP2 16    // per (node,partition) bucket; deg/part ~ Poisson(2)
#define SCAP 64    // per-node spill capacity (correctness fallback, ~never used)
#define EILP 8     // edges per scatter thread

// ---------------- K1: zero cursors + edge dtype detect ----------------
__global__ __launch_bounds__(256) void init_detect_kernel(const unsigned int* __restrict__ w,
                                                          int n_pairs, int n,
                                                          int* __restrict__ cursor,   // [NPART*n]
                                                          int* __restrict__ scursor,  // [n]
                                                          int* __restrict__ flag) {
    int i = blockIdx.x * 256 + threadIdx.x;
    if (i < n) {
        #pragma unroll
        for (int p = 0; p < NPART; ++p) cursor[(size_t)p * n + i] = 0;
        scursor[i] = 0;
    }
    if (blockIdx.x == 0) {
        __shared__ int any_sh;
        int t = threadIdx.x;
        if (t == 0) any_sh = 0;
        __syncthreads();
        unsigned int acc = 0;
        int lim = n_pairs < 8192 ? n_pairs : 8192;
        for (int k = t; k < lim; k += 256) acc |= w[2 * k + 1];
        if (__any(acc != 0)) {
            if ((t & 63) == 0) any_sh = 1;
        }
        __syncthreads();
        if (t == 0) *flag = any_sh ? 1 : 0;   // int64 edges: zero high halves -> 0
    }
}

// ---------------- K2: fused GEMM (blocks [0,gb)) + XCD-partitioned scatter --------
template<typename IdxT>
__global__ __launch_bounds__(256) void gemm_scatter_kernel(const float* __restrict__ X,
                                                           const float* __restrict__ W,
                                                           const float* __restrict__ ka,
                                                           unsigned short* __restrict__ h16,
                                                           float* __restrict__ a,
                                                           float* __restrict__ b, int n,
                                                           const void* __restrict__ eraw,
                                                           const int* __restrict__ flag,
                                                           int* __restrict__ cursor,
                                                           int* __restrict__ scursor,
                                                           IdxT* __restrict__ bucket,  // [(NPART*n)*CAP2], partition-major
                                                           IdxT* __restrict__ spill,   // [n*SCAP]
                                                           int E, int gemm_blocks, int scat_threads) {
    if ((int)blockIdx.x >= gemm_blocks) {
        // ---- scatter path: 8 edges/thread; partition = blockIdx&7 (== this XCD) ----
        int p = (int)(blockIdx.x & (NPART - 1));
        int tid = ((int)blockIdx.x - gemm_blocks) * 256 + threadIdx.x;
        bool e32 = (*flag != 0);
        int tgts[EILP], nbrs[EILP];
        #pragma unroll
        for (int k = 0; k < EILP; ++k) {
            int e = tid + k * scat_threads;
            tgts[k] = -1;
            if (e < E) {
                if (e32) {
                    uint2 q = ((const uint2*)eraw)[e];
                    tgts[k] = (int)q.x; nbrs[k] = (int)q.y;
                } else {
                    uint4 q = ((const uint4*)eraw)[e];   // int64 pair: lows at x,z
                    tgts[k] = (int)q.x; nbrs[k] = (int)q.z;
                }
            }
        }
        int slot[EILP];
        #pragma unroll
        for (int k = 0; k < EILP; ++k)
            if (tgts[k] >= 0) slot[k] = atomicAdd(&cursor[(size_t)p * n + tgts[k]], 1);
        #pragma unroll
        for (int k = 0; k < EILP; ++k) {
            if (tgts[k] < 0) continue;
            if (slot[k] < CAP2) {
                bucket[((size_t)p * n + tgts[k]) * CAP2 + slot[k]] = (IdxT)nbrs[k];
            } else {                                     // ~never: spill, still correct
                int ss = atomicAdd(&scursor[tgts[k]], 1);
                if (ss < SCAP) spill[(size_t)tgts[k] * SCAP + ss] = (IdxT)nbrs[k];
            }
        }
        return;
    }

    // ---- gemm path ----
    __shared__ float Xs[128][36];
    int brow = blockIdx.x * 32;
    int t = threadIdx.x;

    #pragma unroll
    for (int i = 0; i < 4; ++i) {
        int idx4 = t + 256 * i;
        int flat = idx4 * 4;
        int r = flat >> 7;
        int k = flat & 127;
        int row = brow + r;
        float4 v = make_float4(0.f, 0.f, 0.f, 0.f);
        if (row < n) v = *(const float4*)(X + (size_t)row * 128 + k);
        Xs[k + 0][r] = v.x; Xs[k + 1][r] = v.y; Xs[k + 2][r] = v.z; Xs[k + 3][r] = v.w;
    }
    __syncthreads();

    int c4 = (t & 31) * 4;
    int rg = (t >> 5) * 4;
    float acc[4][4] = {{0.f}};

    #pragma unroll 4
    for (int k = 0; k < 128; ++k) {
        float4 xv = *(const float4*)(&Xs[k][rg]);
        float4 wv = *(const float4*)(W + k * 128 + c4);
        float xr[4] = {xv.x, xv.y, xv.z, xv.w};
        float wc[4] = {wv.x, wv.y, wv.z, wv.w};
        #pragma unroll
        for (int r = 0; r < 4; ++r)
            #pragma unroll
            for (int c = 0; c < 4; ++c)
                acc[r][c] += xr[r] * wc[c];
    }

    #pragma unroll
    for (int r = 0; r < 4; ++r) {
        int row = brow + rg + r;
        if (row < n) {
            union { unsigned short u[4]; uint2 v; } pk;
            #pragma unroll
            for (int c = 0; c < 4; ++c)
                pk.u[c] = __bfloat16_as_ushort(__float2bfloat16(acc[r][c]));
            *(uint2*)(h16 + (size_t)row * 128 + c4) = pk.v;
        }
    }

    float ka1[4], ka2[4];
    #pragma unroll
    for (int i = 0; i < 4; ++i) { ka1[i] = ka[c4 + i]; ka2[i] = ka[128 + c4 + i]; }
    #pragma unroll
    for (int r = 0; r < 4; ++r) {
        float pa = acc[r][0] * ka1[0] + acc[r][1] * ka1[1] + acc[r][2] * ka1[2] + acc[r][3] * ka1[3];
        float pb = acc[r][0] * ka2[0] + acc[r][1] * ka2[1] + acc[r][2] * ka2[2] + acc[r][3] * ka2[3];
        #pragma unroll
        for (int off = 16; off; off >>= 1) {
            pa += __shfl_xor(pa, off, 64);
            pb += __shfl_xor(pb, off, 64);
        }
        int row = brow + rg + r;
        if ((t & 31) == 0 && row < n) { a[row] = pa; b[row] = pb; }
    }
}

// ---------------- K3: aggregation — reconstruct edge list from 8 sub-buckets ------
template<typename IdxT>
__global__ __launch_bounds__(256) void aggregate_kernel(const unsigned short* __restrict__ h16,
                                                        const float* __restrict__ a,
                                                        const float* __restrict__ b,
                                                        const int* __restrict__ cursor,
                                                        const int* __restrict__ scursor,
                                                        const IdxT* __restrict__ bucket,
                                                        const IdxT* __restrict__ spill,
                                                        float* __restrict__ out, int n) {
    int wid = threadIdx.x >> 6, lane = threadIdx.x & 63;
    int v = blockIdx.x * 4 + wid;
    if (v >= n) return;

    // per-partition counts -> exclusive prefix (static-indexed, stays in regs)
    int cum[NPART + 1];
    cum[0] = 0;
    #pragma unroll
    for (int p = 0; p < NPART; ++p) {
        int c = cursor[(size_t)p * n + v];
        c = c < CAP2 ? c : CAP2;
        cum[p + 1] = cum[p] + c;
    }
    int sd = scursor[v]; sd = sd < SCAP ? sd : SCAP;
    int d = cum[NPART] + sd;

    float av = a[v];
    int sub = lane >> 4;
    int l16 = lane & 15;

    float ssum = 0.f;
    float acc[8];
    #pragma unroll
    for (int i = 0; i < 8; ++i) acc[i] = 0.f;

    for (int base = 0; base < d; base += 64) {
        int m = min(64, d - base);
        int nb = 0; float sv = 0.f;
        if (lane < m) {
            int ii = base + lane;
            int pidx = 0, pofs = 0;
            #pragma unroll
            for (int q = 1; q <= NPART; ++q) {       // static cum[q] each iter
                bool ge = (ii >= cum[q]);
                pidx += ge ? 1 : 0;
                pofs  = ge ? cum[q] : pofs;
            }
            int idx = ii - pofs;
            if (pidx < NPART) nb = (int)bucket[((size_t)pidx * n + v) * CAP2 + idx];
            else              nb = (int)spill[(size_t)v * SCAP + idx];
            float sc = av + b[nb];
            sc = (sc >= 0.f) ? sc : LEAKY * sc;      // leaky_relu
            sc = fminf(fmaxf(sc, -2.f), 2.f);        // clip
            sv = __expf(sc);
        }
        ssum += sv;
        for (int j4 = 0; j4 < m; j4 += 4) {
            int j = j4 + sub;
            int nbj = __shfl(nb, j, 64);
            float wj = __shfl(sv, j, 64);
            uint4 hv = *(const uint4*)(h16 + (size_t)nbj * 128 + l16 * 8);
            acc[0] += wj * __uint_as_float(hv.x << 16);
            acc[1] += wj * __uint_as_float(hv.x & 0xffff0000u);
            acc[2] += wj * __uint_as_float(hv.y << 16);
            acc[3] += wj * __uint_as_float(hv.y & 0xffff0000u);
            acc[4] += wj * __uint_as_float(hv.z << 16);
            acc[5] += wj * __uint_as_float(hv.z & 0xffff0000u);
            acc[6] += wj * __uint_as_float(hv.w << 16);
            acc[7] += wj * __uint_as_float(hv.w & 0xffff0000u);
        }
    }

    #pragma unroll
    for (int off = 32; off; off >>= 1) ssum += __shfl_xor(ssum, off, 64);
    #pragma unroll
    for (int i = 0; i < 8; ++i) {
        acc[i] += __shfl_xor(acc[i], 16, 64);
        acc[i] += __shfl_xor(acc[i], 32, 64);
    }
    float inv = 1.f / (ssum + EPSF);
    float o0 = (sub == 0) ? acc[0] : (sub == 1) ? acc[2] : (sub == 2) ? acc[4] : acc[6];
    float o1 = (sub == 0) ? acc[1] : (sub == 1) ? acc[3] : (sub == 2) ? acc[5] : acc[7];
    float2 o = make_float2(o0 * inv, o1 * inv);
    *(float2*)(out + (size_t)v * 128 + l16 * 8 + sub * 2) = o;
}

extern "C" void kernel_launch(void* const* d_in, const int* in_sizes, int n_in,
                              void* d_out, int out_size, void* d_ws, size_t ws_size,
                              hipStream_t stream) {
    const float* X     = (const float*)d_in[0];
    const void*  edges = d_in[1];
    const float* W     = (const float*)d_in[2];
    const float* ka    = (const float*)d_in[3];
    float* out = (float*)d_out;

    int n_nodes = in_sizes[0] / 128;
    int E       = in_sizes[1] / 2;

    char* ws = (char*)d_ws;
    size_t off = 0;
    auto alloc = [&](size_t bytes) { size_t o = off; off = (off + bytes + 255) & ~(size_t)255; return o; };
    unsigned short* h16 = (unsigned short*)(ws + alloc((size_t)n_nodes * 128 * 2));
    float* a      = (float*)(ws + alloc((size_t)n_nodes * 4));
    float* b      = (float*)(ws + alloc((size_t)n_nodes * 4));
    int*   cursor = (int*)  (ws + alloc((size_t)NPART * n_nodes * 4));
    int*   scursor= (int*)  (ws + alloc((size_t)n_nodes * 4));
    size_t idxsz  = (n_nodes <= 65536) ? 2 : 4;
    void*  bucket = (void*) (ws + alloc((size_t)NPART * n_nodes * CAP2 * idxsz));
    void*  spill  = (void*) (ws + alloc((size_t)n_nodes * SCAP * idxsz));
    int*   flag   = (int*)  (ws + alloc(4));

    int ib = (n_nodes + 255) / 256;
    int gb = (n_nodes + 31) / 32;
    int sb = (E + EILP * 256 - 1) / (EILP * 256);
    int st = sb * 256;
    int ab = (n_nodes + 3) / 4;

    init_detect_kernel<<<ib, 256, 0, stream>>>((const unsigned int*)edges, E, n_nodes,
                                               cursor, scursor, flag);

    if (n_nodes <= 65536) {
        gemm_scatter_kernel<unsigned short><<<gb + sb, 256, 0, stream>>>(
            X, W, ka, h16, a, b, n_nodes, edges, flag, cursor, scursor,
            (unsigned short*)bucket, (unsigned short*)spill, E, gb, st);
        aggregate_kernel<unsigned short><<<ab, 256, 0, stream>>>(
            h16, a, b, cursor, scursor, (const unsigned short*)bucket,
            (const unsigned short*)spill, out, n_nodes);
    } else {
        gemm_scatter_kernel<unsigned int><<<gb + sb, 256, 0, stream>>>(
            X, W, ka, h16, a, b, n_nodes, edges, flag, cursor, scursor,
            (unsigned int*)bucket, (unsigned int*)spill, E, gb, st);
        aggregate_kernel<unsigned int><<<ab, 256, 0, stream>>>(
            h16, a, b, cursor, scursor, (const unsigned int*)bucket,
            (const unsigned int*)spill, out, n_nodes);
    }
}